// Round 5
// baseline (672.376 us; speedup 1.0000x reference)
//
#include <hip/hip_runtime.h>
#include <cstdint>
#include <cstddef>

// ---------------------------------------------------------------------------
// GCN regression, fp32. Round 5: sliced feature layout [D/8][N][8].
//   R4 profile: gathers fetch 189MB HBM vs 25.6MB array (random src over a
//   working set >> 4MiB per-XCD L2). Slice features into 8-dim blocks
//   (3.2MB/slice, L2-resident); slice = blockIdx % NS rides the round-robin
//   block->XCD mapping so each XCD keeps one slice hot. Gather = 1 thread per
//   (node, slice), edge loop unrolled x4 (8 float4 loads in flight).
//   GEMM/scale/pool read+write the sliced layout (H1 row-major, GEMM-only).
// ---------------------------------------------------------------------------

#define BKT_LG 10
#define BKT_SZ 1024
#define BIN_CHUNK 2048

__device__ __forceinline__ void f4add(float4& a, const float4& v) {
    a.x += v.x; a.y += v.y; a.z += v.z; a.w += v.w;
}

// ---- bucket histogram: bcnt[b] = #edges with dst in bucket b
static __global__ void bhist_kernel(const int* __restrict__ dst, int* __restrict__ bcnt,
                                    int E, int NB) {
    __shared__ int h[128];
    for (int i = threadIdx.x; i < NB; i += 256) h[i] = 0;
    __syncthreads();
    for (int t = blockIdx.x * 256 + threadIdx.x; t < E; t += gridDim.x * 256)
        atomicAdd(&h[dst[t] >> BKT_LG], 1);
    __syncthreads();
    for (int i = threadIdx.x; i < NB; i += 256)
        if (h[i]) atomicAdd(&bcnt[i], h[i]);
}

// ---- exclusive scan of bcnt -> base (NB+1), bfill = base  (single block)
static __global__ void bscan_kernel(const int* __restrict__ bcnt, int* __restrict__ base,
                                    int* __restrict__ bfill, int NB, int E) {
    __shared__ int s[128];
    int t = threadIdx.x;
    int v = (t < NB) ? bcnt[t] : 0;
    s[t] = v;
    __syncthreads();
    for (int off = 1; off < 128; off <<= 1) {
        int u = (t >= off) ? s[t - off] : 0;
        __syncthreads();
        s[t] += u;
        __syncthreads();
    }
    if (t < NB) { base[t] = s[t] - v; bfill[t] = s[t] - v; }
    if (t == 0) base[NB] = E;
}

// ---- bin edges into bucket-contiguous runs
__launch_bounds__(256)
static __global__ void bin_kernel(const int* __restrict__ src, const int* __restrict__ dst,
                                  int* __restrict__ bfill, unsigned* __restrict__ binned,
                                  int E, int NB) {
    __shared__ int h[128];
    __shared__ int res[128];
    const int beg = blockIdx.x * BIN_CHUNK;
    const int ce = min(BIN_CHUNK, E - beg);
    for (int i = threadIdx.x; i < NB; i += 256) h[i] = 0;
    __syncthreads();
    for (int i = threadIdx.x; i < ce; i += 256)
        atomicAdd(&h[dst[beg + i] >> BKT_LG], 1);
    __syncthreads();
    for (int i = threadIdx.x; i < NB; i += 256) {
        res[i] = h[i] ? atomicAdd(&bfill[i], h[i]) : 0;
        h[i] = 0;
    }
    __syncthreads();
    for (int i = threadIdx.x; i < ce; i += 256) {
        int d = dst[beg + i];
        int b = d >> BKT_LG;
        int p = res[b] + atomicAdd(&h[b], 1);
        binned[p] = ((unsigned)src[beg + i] << BKT_LG) | (unsigned)(d & (BKT_SZ - 1));
    }
}

// ---- per-bucket: count per node, scan, emit rowptr/dinv, group col
__launch_bounds__(256)
static __global__ void group_kernel(const unsigned* __restrict__ binned, const int* __restrict__ base,
                                    int* __restrict__ rowptr, int* __restrict__ col,
                                    float* __restrict__ dinv, int N, int E) {
    __shared__ int cnt[BKT_SZ];
    __shared__ int ex[BKT_SZ];
    __shared__ int ps[256];
    const int tid = threadIdx.x;
    const int b = blockIdx.x;
    const int node0 = b << BKT_LG;
    const int nn = min(BKT_SZ, N - node0);
    const int beg = base[b], end = base[b + 1];

    for (int i = tid; i < BKT_SZ; i += 256) cnt[i] = 0;
    __syncthreads();
    for (int i = beg + tid; i < end; i += 256)
        atomicAdd(&cnt[binned[i] & (BKT_SZ - 1)], 1);
    __syncthreads();

    const int b4 = tid * 4;
    int c0 = cnt[b4], c1 = cnt[b4 + 1], c2 = cnt[b4 + 2], c3 = cnt[b4 + 3];
    int s01 = c0 + c1;
    int s = s01 + c2 + c3;
    ps[tid] = s;
    __syncthreads();
    for (int off = 1; off < 256; off <<= 1) {
        int u = (tid >= off) ? ps[tid - off] : 0;
        __syncthreads();
        ps[tid] += u;
        __syncthreads();
    }
    int excl = ps[tid] - s;
    ex[b4]     = excl;
    ex[b4 + 1] = excl + c0;
    ex[b4 + 2] = excl + s01;
    ex[b4 + 3] = excl + s01 + c2;
    __syncthreads();

    for (int i = tid; i < nn; i += 256) {
        rowptr[node0 + i] = beg + ex[i];
        dinv[node0 + i] = rsqrtf((float)cnt[i] + 1.0f);
    }
    if (b == 0 && tid == 0) rowptr[N] = E;
    __syncthreads();

    for (int i = beg + tid; i < end; i += 256) {
        unsigned v = binned[i];
        int dl = v & (BKT_SZ - 1);
        int p = atomicAdd(&ex[dl], 1);
        col[beg + p] = (int)(v >> BKT_LG);
    }
}

// o_sliced[(c>>3)][row][c&7] = x[row][c] * dinv[row], dim 64 row-major input
static __global__ void scale_kernel(const float* __restrict__ x, const float* __restrict__ dinv,
                                    float* __restrict__ o, int N) {
    int t = blockIdx.x * 256 + threadIdx.x;
    if (t >= N * 16) return;
    int row = t >> 4;
    int c = (t & 15) * 4;
    float d = dinv[row];
    float4 v = *(const float4*)&x[(size_t)row * 64 + c];
    v.x *= d; v.y *= d; v.z *= d; v.w *= d;
    *(float4*)&o[((size_t)(c >> 3) * N + row) * 8 + (c & 7)] = v;
}

// Sliced gather: hsS/outS layout [NS][N][8]. slice = blockIdx % NS (XCD affinity).
// out[n] = dinv[n]*(sum_{s->n} hs[s] + hs[n])  [+bias, relu if BR]
template <int NS, bool BR>
__launch_bounds__(256)
static __global__ void gather_slice_kernel(const float* __restrict__ hsS, const int* __restrict__ rowptr,
                                           const int* __restrict__ col, const float* __restrict__ dinv,
                                           const float* __restrict__ bias, float* __restrict__ outS,
                                           int N) {
    const int s = blockIdx.x % NS;
    const int n = (blockIdx.x / NS) * 256 + threadIdx.x;
    if (n >= N) return;
    const float* __restrict__ base = hsS + (size_t)s * N * 8;
    const int beg = rowptr[n], end = rowptr[n + 1];
    float4 a0 = *(const float4*)&base[(size_t)n * 8 + 0];   // self loop
    float4 a1 = *(const float4*)&base[(size_t)n * 8 + 4];
    float4 b0 = make_float4(0.f, 0.f, 0.f, 0.f);
    float4 b1 = make_float4(0.f, 0.f, 0.f, 0.f);
    int e = beg;
    for (; e + 4 <= end; e += 4) {
        int c0 = col[e], c1 = col[e + 1], c2 = col[e + 2], c3 = col[e + 3];
        const float4* p0 = (const float4*)&base[(size_t)c0 * 8];
        const float4* p1 = (const float4*)&base[(size_t)c1 * 8];
        const float4* p2 = (const float4*)&base[(size_t)c2 * 8];
        const float4* p3 = (const float4*)&base[(size_t)c3 * 8];
        float4 v00 = p0[0], v01 = p0[1];
        float4 v10 = p1[0], v11 = p1[1];
        float4 v20 = p2[0], v21 = p2[1];
        float4 v30 = p3[0], v31 = p3[1];
        f4add(a0, v00); f4add(a1, v01);
        f4add(b0, v10); f4add(b1, v11);
        f4add(a0, v20); f4add(a1, v21);
        f4add(b0, v30); f4add(b1, v31);
    }
    for (; e < end; ++e) {
        const float4* p = (const float4*)&base[(size_t)col[e] * 8];
        f4add(a0, p[0]); f4add(a1, p[1]);
    }
    f4add(a0, b0); f4add(a1, b1);
    float dv = dinv[n];
    float4 r0, r1;
    r0.x = a0.x * dv; r0.y = a0.y * dv; r0.z = a0.z * dv; r0.w = a0.w * dv;
    r1.x = a1.x * dv; r1.y = a1.y * dv; r1.z = a1.z * dv; r1.w = a1.w * dv;
    if (BR) {
        float4 bv0 = *(const float4*)&bias[s * 8 + 0];
        float4 bv1 = *(const float4*)&bias[s * 8 + 4];
        r0.x = fmaxf(r0.x + bv0.x, 0.f); r0.y = fmaxf(r0.y + bv0.y, 0.f);
        r0.z = fmaxf(r0.z + bv0.z, 0.f); r0.w = fmaxf(r0.w + bv0.w, 0.f);
        r1.x = fmaxf(r1.x + bv1.x, 0.f); r1.y = fmaxf(r1.y + bv1.y, 0.f);
        r1.z = fmaxf(r1.z + bv1.z, 0.f); r1.w = fmaxf(r1.w + bv1.w, 0.f);
    }
    float* op = outS + ((size_t)s * N + n) * 8;
    *(float4*)&op[0] = r0;
    *(float4*)&op[4] = r1;
}

// out = Xin @ W (+epilogue). W fully in LDS. ISL/OSL: sliced in/out layout.
// MODE 0: out = relu(acc + bias[col]);  MODE 1: out = acc * dinv[row]
template <int K, int OUT, int RT, int MODE, bool ISL, bool OSL>
__launch_bounds__(256)
static __global__ void gemm_kernel(const float* __restrict__ Xin, const float* __restrict__ W,
                                   const float* __restrict__ bias, const float* __restrict__ dinv,
                                   float* __restrict__ out, int N) {
    constexpr int CT = OUT / 4;
    constexpr int RTH = 256 / CT;
    constexpr int RB = RTH * RT;
    constexpr int KP = K + 4;
    __shared__ float Wl[K * OUT];
    __shared__ float Xl[RB * KP];

    const int tid = threadIdx.x;
    const int row0 = blockIdx.x * RB;

    for (int idx = tid; idx < K * OUT / 4; idx += 256)
        ((float4*)Wl)[idx] = ((const float4*)W)[idx];

    constexpr int KC = K / 4;
    for (int idx = tid; idx < RB * KC; idx += 256) {
        int r = idx / KC;
        int kc = idx - r * KC;
        int g = row0 + r;
        float4 v = make_float4(0.f, 0.f, 0.f, 0.f);
        if (g < N) {
            if (ISL) {
                int k4 = kc * 4;
                v = *(const float4*)&Xin[((size_t)(k4 >> 3) * N + g) * 8 + (k4 & 7)];
            } else {
                v = ((const float4*)(Xin + (size_t)g * K))[kc];
            }
        }
        *(float4*)&Xl[r * KP + kc * 4] = v;
    }
    __syncthreads();

    const int tx = tid % CT, ty = tid / CT;
    const int col0 = tx * 4;
    float4 acc[RT];
#pragma unroll
    for (int i = 0; i < RT; i++) acc[i] = make_float4(0.f, 0.f, 0.f, 0.f);

#pragma unroll 4
    for (int k = 0; k < K; k += 4) {
        float4 w0 = *(float4*)&Wl[(k + 0) * OUT + col0];
        float4 w1 = *(float4*)&Wl[(k + 1) * OUT + col0];
        float4 w2 = *(float4*)&Wl[(k + 2) * OUT + col0];
        float4 w3 = *(float4*)&Wl[(k + 3) * OUT + col0];
#pragma unroll
        for (int i = 0; i < RT; i++) {
            float4 xv = *(float4*)&Xl[(ty * RT + i) * KP + k];
            acc[i].x += xv.x * w0.x + xv.y * w1.x + xv.z * w2.x + xv.w * w3.x;
            acc[i].y += xv.x * w0.y + xv.y * w1.y + xv.z * w2.y + xv.w * w3.y;
            acc[i].z += xv.x * w0.z + xv.y * w1.z + xv.z * w2.z + xv.w * w3.z;
            acc[i].w += xv.x * w0.w + xv.y * w1.w + xv.z * w2.w + xv.w * w3.w;
        }
    }

#pragma unroll
    for (int i = 0; i < RT; i++) {
        int g = row0 + ty * RT + i;
        if (g >= N) continue;
        float4 r;
        if (MODE == 0) {
            float4 bv = *(const float4*)&bias[col0];
            r.x = fmaxf(acc[i].x + bv.x, 0.f);
            r.y = fmaxf(acc[i].y + bv.y, 0.f);
            r.z = fmaxf(acc[i].z + bv.z, 0.f);
            r.w = fmaxf(acc[i].w + bv.w, 0.f);
        } else {
            float d = dinv[g];
            r.x = acc[i].x * d; r.y = acc[i].y * d;
            r.z = acc[i].z * d; r.w = acc[i].w * d;
        }
        if (OSL)
            *(float4*)&out[((size_t)(col0 >> 3) * N + g) * 8 + (col0 & 7)] = r;
        else
            *(float4*)&out[(size_t)g * OUT + col0] = r;
    }
}

// pool over sliced h [4][N][8]: per-node dot with Wfc, segment mean (batch sorted)
static __global__ void pool_kernel(const float* __restrict__ h, const float* __restrict__ Wfc,
                                   const int* __restrict__ batch, float* __restrict__ psum,
                                   int* __restrict__ pcnt, int N) {
    __shared__ float wl[32];
    __shared__ float gsum[64];
    __shared__ int gcnt[64];
    __shared__ int sbase;
    int tid = threadIdx.x;
    if (tid < 32) wl[tid] = Wfc[tid];
    if (tid < 64) { gsum[tid] = 0.f; gcnt[tid] = 0; }
    if (tid == 0) sbase = batch[blockIdx.x * 256];
    __syncthreads();

    int n = blockIdx.x * 256 + tid;
    if (n < N) {
        float val = 0.f;
#pragma unroll
        for (int sl = 0; sl < 4; sl++) {
            const float4* hp = (const float4*)&h[((size_t)sl * N + n) * 8];
            float4 h0 = hp[0], h1 = hp[1];
            val += h0.x * wl[sl * 8 + 0] + h0.y * wl[sl * 8 + 1] +
                   h0.z * wl[sl * 8 + 2] + h0.w * wl[sl * 8 + 3] +
                   h1.x * wl[sl * 8 + 4] + h1.y * wl[sl * 8 + 5] +
                   h1.z * wl[sl * 8 + 6] + h1.w * wl[sl * 8 + 7];
        }
        int g = batch[n];
        int rel = g - sbase;
        if ((unsigned)rel < 64u) {
            atomicAdd(&gsum[rel], val);
            atomicAdd(&gcnt[rel], 1);
        } else {
            unsafeAtomicAdd(&psum[g], val);
            atomicAdd(&pcnt[g], 1);
        }
    }
    __syncthreads();
    if (tid < 64 && gcnt[tid] > 0) {
        unsafeAtomicAdd(&psum[sbase + tid], gsum[tid]);
        atomicAdd(&pcnt[sbase + tid], gcnt[tid]);
    }
}

static __global__ void final_kernel(const float* __restrict__ psum, const int* __restrict__ pcnt,
                                    const float* __restrict__ bfc, float* __restrict__ out, int G) {
    int t = threadIdx.x;
    if (t < G) {
        float c = (float)pcnt[t];
        out[t] = psum[t] / fmaxf(c, 1.f) + bfc[0];
    }
}

extern "C" void kernel_launch(void* const* d_in, const int* in_sizes, int n_in,
                              void* d_out, int out_size, void* d_ws, size_t ws_size,
                              hipStream_t stream) {
    const float* x    = (const float*)d_in[0];
    const int*   ei   = (const int*)d_in[1];
    const int*   batch= (const int*)d_in[2];
    const float* W1   = (const float*)d_in[4];
    const float* b1   = (const float*)d_in[5];
    const float* W2   = (const float*)d_in[6];
    const float* b2   = (const float*)d_in[7];
    const float* W3   = (const float*)d_in[8];
    const float* b3   = (const float*)d_in[9];
    const float* W4   = (const float*)d_in[10];
    const float* b4   = (const float*)d_in[11];
    const float* Wfc  = (const float*)d_in[12];
    const float* bfc  = (const float*)d_in[13];
    float* out = (float*)d_out;

    const int N = in_sizes[0] / 64;
    const int E = in_sizes[1] / 2;
    const int G = out_size;
    const int* srcp = ei;
    const int* dstp = ei + E;
    const int NB = (N + BKT_SZ - 1) >> BKT_LG;   // 98 for N=100k

    // workspace layout (float-sized slots)
    float* wsf = (float*)d_ws;
    const size_t Npad = ((size_t)N + 1023) / 1024 * 1024;
    const size_t Epad = ((size_t)E + 1023) / 1024 * 1024;
    float*    dinv   = wsf;                            // Npad
    int*      rowptr = (int*)(wsf + Npad);             // Npad + 1024
    int*      col    = (int*)(wsf + 2 * Npad + 1024);  // Epad
    unsigned* binned = (unsigned*)((float*)col + Epad);// Epad
    int*      bcnt   = (int*)((float*)binned + Epad);  // 256
    int*      base   = bcnt + 256;                     // 256
    int*      bfill  = base + 256;                     // 256
    float*    psum   = (float*)(bfill + 256);          // 256
    int*      pcnt   = (int*)(psum + 256);             // 256
    float*    T1     = psum + 1024;                    // Npad*64
    float*    T2     = T1 + Npad * 64;                 // Npad*64
    float*    H1     = T2 + Npad * 64;                 // Npad*128

    const int gN    = (N + 255) / 256;
    const int gN16  = (N * 16 + 255) / 256;
    const int nbin  = (E + BIN_CHUNK - 1) / BIN_CHUNK;
    const int gSl8  = gN * 8;   // sliced gather grids
    const int gSl4  = gN * 4;

    hipMemsetAsync(bcnt, 0, 256 * sizeof(int), stream);
    hipMemsetAsync(psum, 0, 512 * sizeof(float), stream);

    // ---- CSR build (by dst, col = src) + dinv
    bhist_kernel<<<256, 256, 0, stream>>>(dstp, bcnt, E, NB);
    bscan_kernel<<<1, 128, 0, stream>>>(bcnt, base, bfill, NB, E);
    bin_kernel<<<nbin, 256, 0, stream>>>(srcp, dstp, bfill, binned, E, NB);
    group_kernel<<<NB, 256, 0, stream>>>(binned, base, rowptr, col, dinv, N, E);

    // ---- layer 1: aggregate X (dim 64, sliced) first, then GEMM 64->128 (+b,relu)
    scale_kernel<<<gN16, 256, 0, stream>>>(x, dinv, T1, N);
    gather_slice_kernel<8, false><<<gSl8, 256, 0, stream>>>(T1, rowptr, col, dinv, nullptr, T2, N);
    gemm_kernel<64, 128, 4, 0, true, false><<<(N + 31) / 32, 256, 0, stream>>>(T2, W1, b1, nullptr, H1, N);

    // ---- layer 2: GEMM 128->64 (x dinv, sliced out), gather(bias+relu)
    gemm_kernel<128, 64, 2, 1, false, true><<<(N + 31) / 32, 256, 0, stream>>>(H1, W2, nullptr, dinv, T1, N);
    gather_slice_kernel<8, true><<<gSl8, 256, 0, stream>>>(T1, rowptr, col, dinv, b2, T2, N);

    // ---- layer 3: GEMM 64->64 sliced->sliced
    gemm_kernel<64, 64, 4, 1, true, true><<<(N + 63) / 64, 256, 0, stream>>>(T2, W3, nullptr, dinv, T1, N);
    gather_slice_kernel<8, true><<<gSl8, 256, 0, stream>>>(T1, rowptr, col, dinv, b3, T2, N);

    // ---- layer 4: GEMM 64->32 sliced->sliced (4 slices)
    gemm_kernel<64, 32, 4, 1, true, true><<<(N + 127) / 128, 256, 0, stream>>>(T2, W4, nullptr, dinv, T1, N);
    gather_slice_kernel<4, true><<<gSl4, 256, 0, stream>>>(T1, rowptr, col, dinv, b4, T2, N);

    // ---- pool + fc
    pool_kernel<<<gN, 256, 0, stream>>>(T2, Wfc, batch, psum, pcnt, N);
    final_kernel<<<1, 256, 0, stream>>>(psum, pcnt, bfc, out, G);
}

// Round 6
// 500.998 us; speedup vs baseline: 1.3421x; 1.3421x over previous
//
#include <hip/hip_runtime.h>
#include <cstdint>
#include <cstddef>

// ---------------------------------------------------------------------------
// GCN regression, fp32. Round 6: revert R5 slicing (FAILED: no XCD affinity,
// sub-line reads); back to R4 row-major + gather MLP fix:
//   R4 gather was latency-bound (VALUBusy 15%, 3.47 TB/s fabric, VGPR=36 ->
//   ~4 loads in flight). Now: explicit float4 v[8] batch per 8-edge chunk ->
//   8 outstanding loads/thread, accumulate after.
// ---------------------------------------------------------------------------

#define BKT_LG 10
#define BKT_SZ 1024
#define BIN_CHUNK 2048

__device__ __forceinline__ void f4add(float4& a, const float4& v) {
    a.x += v.x; a.y += v.y; a.z += v.z; a.w += v.w;
}

// ---- bucket histogram: bcnt[b] = #edges with dst in bucket b
static __global__ void bhist_kernel(const int* __restrict__ dst, int* __restrict__ bcnt,
                                    int E, int NB) {
    __shared__ int h[128];
    for (int i = threadIdx.x; i < NB; i += 256) h[i] = 0;
    __syncthreads();
    for (int t = blockIdx.x * 256 + threadIdx.x; t < E; t += gridDim.x * 256)
        atomicAdd(&h[dst[t] >> BKT_LG], 1);
    __syncthreads();
    for (int i = threadIdx.x; i < NB; i += 256)
        if (h[i]) atomicAdd(&bcnt[i], h[i]);
}

// ---- exclusive scan of bcnt -> base (NB+1), bfill = base  (single block)
static __global__ void bscan_kernel(const int* __restrict__ bcnt, int* __restrict__ base,
                                    int* __restrict__ bfill, int NB, int E) {
    __shared__ int s[128];
    int t = threadIdx.x;
    int v = (t < NB) ? bcnt[t] : 0;
    s[t] = v;
    __syncthreads();
    for (int off = 1; off < 128; off <<= 1) {
        int u = (t >= off) ? s[t - off] : 0;
        __syncthreads();
        s[t] += u;
        __syncthreads();
    }
    if (t < NB) { base[t] = s[t] - v; bfill[t] = s[t] - v; }
    if (t == 0) base[NB] = E;
}

// ---- bin edges into bucket-contiguous runs
__launch_bounds__(256)
static __global__ void bin_kernel(const int* __restrict__ src, const int* __restrict__ dst,
                                  int* __restrict__ bfill, unsigned* __restrict__ binned,
                                  int E, int NB) {
    __shared__ int h[128];
    __shared__ int res[128];
    const int beg = blockIdx.x * BIN_CHUNK;
    const int ce = min(BIN_CHUNK, E - beg);
    for (int i = threadIdx.x; i < NB; i += 256) h[i] = 0;
    __syncthreads();
    for (int i = threadIdx.x; i < ce; i += 256)
        atomicAdd(&h[dst[beg + i] >> BKT_LG], 1);
    __syncthreads();
    for (int i = threadIdx.x; i < NB; i += 256) {
        res[i] = h[i] ? atomicAdd(&bfill[i], h[i]) : 0;
        h[i] = 0;
    }
    __syncthreads();
    for (int i = threadIdx.x; i < ce; i += 256) {
        int d = dst[beg + i];
        int b = d >> BKT_LG;
        int p = res[b] + atomicAdd(&h[b], 1);
        binned[p] = ((unsigned)src[beg + i] << BKT_LG) | (unsigned)(d & (BKT_SZ - 1));
    }
}

// ---- per-bucket: count per node, scan, emit rowptr/dinv, group col
__launch_bounds__(256)
static __global__ void group_kernel(const unsigned* __restrict__ binned, const int* __restrict__ base,
                                    int* __restrict__ rowptr, int* __restrict__ col,
                                    float* __restrict__ dinv, int N, int E) {
    __shared__ int cnt[BKT_SZ];
    __shared__ int ex[BKT_SZ];
    __shared__ int ps[256];
    const int tid = threadIdx.x;
    const int b = blockIdx.x;
    const int node0 = b << BKT_LG;
    const int nn = min(BKT_SZ, N - node0);
    const int beg = base[b], end = base[b + 1];

    for (int i = tid; i < BKT_SZ; i += 256) cnt[i] = 0;
    __syncthreads();
    for (int i = beg + tid; i < end; i += 256)
        atomicAdd(&cnt[binned[i] & (BKT_SZ - 1)], 1);
    __syncthreads();

    const int b4 = tid * 4;
    int c0 = cnt[b4], c1 = cnt[b4 + 1], c2 = cnt[b4 + 2], c3 = cnt[b4 + 3];
    int s01 = c0 + c1;
    int s = s01 + c2 + c3;
    ps[tid] = s;
    __syncthreads();
    for (int off = 1; off < 256; off <<= 1) {
        int u = (tid >= off) ? ps[tid - off] : 0;
        __syncthreads();
        ps[tid] += u;
        __syncthreads();
    }
    int excl = ps[tid] - s;
    ex[b4]     = excl;
    ex[b4 + 1] = excl + c0;
    ex[b4 + 2] = excl + s01;
    ex[b4 + 3] = excl + s01 + c2;
    __syncthreads();

    for (int i = tid; i < nn; i += 256) {
        rowptr[node0 + i] = beg + ex[i];
        dinv[node0 + i] = rsqrtf((float)cnt[i] + 1.0f);
    }
    if (b == 0 && tid == 0) rowptr[N] = E;
    __syncthreads();

    for (int i = beg + tid; i < end; i += 256) {
        unsigned v = binned[i];
        int dl = v & (BKT_SZ - 1);
        int p = atomicAdd(&ex[dl], 1);
        col[beg + p] = (int)(v >> BKT_LG);
    }
}

// o[row] = x[row] * dinv[row], dim 64
static __global__ void scale_kernel(const float* __restrict__ x, const float* __restrict__ dinv,
                                    float* __restrict__ o, int N) {
    int t = blockIdx.x * 256 + threadIdx.x;
    if (t >= N * 16) return;
    int row = t >> 4;
    int c = (t & 15) * 4;
    float d = dinv[row];
    float4 v = *(const float4*)&x[(size_t)row * 64 + c];
    v.x *= d; v.y *= d; v.z *= d; v.w *= d;
    *(float4*)&o[(size_t)row * 64 + c] = v;
}

// out[d] = dinv[d]*(sum_{s in row d} hs[s] + hs[d])  [+bias, relu if BR]
// D4 threads per node. 8-edge chunks: 8 independent float4 loads batched in
// v[8] (8 outstanding misses/thread), then reduced. Predicated tail.
template <int D4, bool BR>
__launch_bounds__(256)
static __global__ void gather_kernel(const float* __restrict__ hs, const int* __restrict__ rowptr,
                                     const int* __restrict__ col, const float* __restrict__ dinv,
                                     const float* __restrict__ b, float* __restrict__ out, int N) {
    constexpr int D = D4 * 4;
    constexpr int NPB = 256 / D4;
    constexpr int LG = (D4 == 16) ? 4 : 3;
    const int lane = threadIdx.x & (D4 - 1);
    const int node = blockIdx.x * NPB + (threadIdx.x >> LG);
    if (node >= N) return;
    const int beg = rowptr[node];
    const int end = rowptr[node + 1];
    float4 acc = *(const float4*)&hs[(size_t)node * D + lane * 4];  // self loop
    float4 acc2 = make_float4(0.f, 0.f, 0.f, 0.f);
    int e = beg;
    for (; e + 8 <= end; e += 8) {
        int myc = col[e + (lane & 7)];
        float4 v[8];
#pragma unroll
        for (int j = 0; j < 8; ++j) {
            int s = __shfl(myc, j, D4);
            v[j] = *(const float4*)&hs[(size_t)s * D + lane * 4];
        }
        f4add(acc, v[0]); f4add(acc2, v[1]);
        f4add(acc, v[2]); f4add(acc2, v[3]);
        f4add(acc, v[4]); f4add(acc2, v[5]);
        f4add(acc, v[6]); f4add(acc2, v[7]);
    }
    {
        const int m = end - e;  // 0..7
        int myc = (e + (lane & 7) < end) ? col[e + (lane & 7)] : 0;
#pragma unroll
        for (int j = 0; j < 7; ++j) {
            if (j < m) {
                int s = __shfl(myc, j, D4);
                float4 vv = *(const float4*)&hs[(size_t)s * D + lane * 4];
                f4add(acc, vv);
            }
        }
    }
    f4add(acc, acc2);
    float dv = dinv[node];
    float4 r;
    r.x = acc.x * dv; r.y = acc.y * dv; r.z = acc.z * dv; r.w = acc.w * dv;
    if (BR) {
        float4 bv = *(const float4*)&b[lane * 4];
        r.x = fmaxf(r.x + bv.x, 0.f);
        r.y = fmaxf(r.y + bv.y, 0.f);
        r.z = fmaxf(r.z + bv.z, 0.f);
        r.w = fmaxf(r.w + bv.w, 0.f);
    }
    *(float4*)&out[(size_t)node * D + lane * 4] = r;
}

// out = Xin @ W (+epilogue). W fully resident in LDS.
// MODE 0: out = relu(acc + bias[col]);  MODE 1: out = acc * dinv[row]
template <int K, int OUT, int RT, int MODE>
__launch_bounds__(256)
static __global__ void gemm_kernel(const float* __restrict__ Xin, const float* __restrict__ W,
                                   const float* __restrict__ bias, const float* __restrict__ dinv,
                                   float* __restrict__ out, int N) {
    constexpr int CT = OUT / 4;
    constexpr int RTH = 256 / CT;
    constexpr int RB = RTH * RT;
    constexpr int KP = K + 4;
    __shared__ float Wl[K * OUT];
    __shared__ float Xl[RB * KP];

    const int tid = threadIdx.x;
    const int row0 = blockIdx.x * RB;

    for (int idx = tid; idx < K * OUT / 4; idx += 256)
        ((float4*)Wl)[idx] = ((const float4*)W)[idx];

    constexpr int KC = K / 4;
    for (int idx = tid; idx < RB * KC; idx += 256) {
        int r = idx / KC;
        int kc = idx - r * KC;
        int g = row0 + r;
        float4 v = (g < N) ? ((const float4*)(Xin + (size_t)g * K))[kc]
                           : make_float4(0.f, 0.f, 0.f, 0.f);
        *(float4*)&Xl[r * KP + kc * 4] = v;
    }
    __syncthreads();

    const int tx = tid % CT, ty = tid / CT;
    const int col0 = tx * 4;
    float4 acc[RT];
#pragma unroll
    for (int i = 0; i < RT; i++) acc[i] = make_float4(0.f, 0.f, 0.f, 0.f);

#pragma unroll 4
    for (int k = 0; k < K; k += 4) {
        float4 w0 = *(float4*)&Wl[(k + 0) * OUT + col0];
        float4 w1 = *(float4*)&Wl[(k + 1) * OUT + col0];
        float4 w2 = *(float4*)&Wl[(k + 2) * OUT + col0];
        float4 w3 = *(float4*)&Wl[(k + 3) * OUT + col0];
#pragma unroll
        for (int i = 0; i < RT; i++) {
            float4 xv = *(float4*)&Xl[(ty * RT + i) * KP + k];
            acc[i].x += xv.x * w0.x + xv.y * w1.x + xv.z * w2.x + xv.w * w3.x;
            acc[i].y += xv.x * w0.y + xv.y * w1.y + xv.z * w2.y + xv.w * w3.y;
            acc[i].z += xv.x * w0.z + xv.y * w1.z + xv.z * w2.z + xv.w * w3.z;
            acc[i].w += xv.x * w0.w + xv.y * w1.w + xv.z * w2.w + xv.w * w3.w;
        }
    }

    if (MODE == 0) {
        float4 bv = *(const float4*)&bias[col0];
#pragma unroll
        for (int i = 0; i < RT; i++) {
            int g = row0 + ty * RT + i;
            if (g < N) {
                float4 r;
                r.x = fmaxf(acc[i].x + bv.x, 0.f);
                r.y = fmaxf(acc[i].y + bv.y, 0.f);
                r.z = fmaxf(acc[i].z + bv.z, 0.f);
                r.w = fmaxf(acc[i].w + bv.w, 0.f);
                *(float4*)&out[(size_t)g * OUT + col0] = r;
            }
        }
    } else {
#pragma unroll
        for (int i = 0; i < RT; i++) {
            int g = row0 + ty * RT + i;
            if (g < N) {
                float d = dinv[g];
                float4 r;
                r.x = acc[i].x * d; r.y = acc[i].y * d;
                r.z = acc[i].z * d; r.w = acc[i].w * d;
                *(float4*)&out[(size_t)g * OUT + col0] = r;
            }
        }
    }
}

static __global__ void pool_kernel(const float* __restrict__ h, const float* __restrict__ Wfc,
                                   const int* __restrict__ batch, float* __restrict__ psum,
                                   int* __restrict__ pcnt, int N) {
    __shared__ float wl[32];
    __shared__ float gsum[64];
    __shared__ int gcnt[64];
    __shared__ int sbase;
    int tid = threadIdx.x;
    if (tid < 32) wl[tid] = Wfc[tid];
    if (tid < 64) { gsum[tid] = 0.f; gcnt[tid] = 0; }
    if (tid == 0) sbase = batch[blockIdx.x * 256];
    __syncthreads();

    int n = blockIdx.x * 256 + tid;
    if (n < N) {
        const float4* hp = (const float4*)(h + (size_t)n * 32);
        float val = 0.f;
#pragma unroll
        for (int j = 0; j < 8; j++) {
            float4 hv = hp[j];
            val += hv.x * wl[j * 4 + 0] + hv.y * wl[j * 4 + 1] +
                   hv.z * wl[j * 4 + 2] + hv.w * wl[j * 4 + 3];
        }
        int g = batch[n];
        int rel = g - sbase;
        if ((unsigned)rel < 64u) {
            atomicAdd(&gsum[rel], val);
            atomicAdd(&gcnt[rel], 1);
        } else {
            unsafeAtomicAdd(&psum[g], val);
            atomicAdd(&pcnt[g], 1);
        }
    }
    __syncthreads();
    if (tid < 64 && gcnt[tid] > 0) {
        unsafeAtomicAdd(&psum[sbase + tid], gsum[tid]);
        atomicAdd(&pcnt[sbase + tid], gcnt[tid]);
    }
}

static __global__ void final_kernel(const float* __restrict__ psum, const int* __restrict__ pcnt,
                                    const float* __restrict__ bfc, float* __restrict__ out, int G) {
    int t = threadIdx.x;
    if (t < G) {
        float c = (float)pcnt[t];
        out[t] = psum[t] / fmaxf(c, 1.f) + bfc[0];
    }
}

extern "C" void kernel_launch(void* const* d_in, const int* in_sizes, int n_in,
                              void* d_out, int out_size, void* d_ws, size_t ws_size,
                              hipStream_t stream) {
    const float* x    = (const float*)d_in[0];
    const int*   ei   = (const int*)d_in[1];
    const int*   batch= (const int*)d_in[2];
    const float* W1   = (const float*)d_in[4];
    const float* b1   = (const float*)d_in[5];
    const float* W2   = (const float*)d_in[6];
    const float* b2   = (const float*)d_in[7];
    const float* W3   = (const float*)d_in[8];
    const float* b3   = (const float*)d_in[9];
    const float* W4   = (const float*)d_in[10];
    const float* b4   = (const float*)d_in[11];
    const float* Wfc  = (const float*)d_in[12];
    const float* bfc  = (const float*)d_in[13];
    float* out = (float*)d_out;

    const int N = in_sizes[0] / 64;
    const int E = in_sizes[1] / 2;
    const int G = out_size;
    const int* srcp = ei;
    const int* dstp = ei + E;
    const int NB = (N + BKT_SZ - 1) >> BKT_LG;   // 98 for N=100k

    // workspace layout (float-sized slots)
    float* wsf = (float*)d_ws;
    const size_t Npad = ((size_t)N + 1023) / 1024 * 1024;
    const size_t Epad = ((size_t)E + 1023) / 1024 * 1024;
    float*    dinv   = wsf;                            // Npad
    int*      rowptr = (int*)(wsf + Npad);             // Npad + 1024
    int*      col    = (int*)(wsf + 2 * Npad + 1024);  // Epad
    unsigned* binned = (unsigned*)((float*)col + Epad);// Epad
    int*      bcnt   = (int*)((float*)binned + Epad);  // 256
    int*      base   = bcnt + 256;                     // 256
    int*      bfill  = base + 256;                     // 256
    float*    psum   = (float*)(bfill + 256);          // 256
    int*      pcnt   = (int*)(psum + 256);             // 256
    float*    T1     = psum + 1024;                    // Npad*64
    float*    T2     = T1 + Npad * 64;                 // Npad*64
    float*    H1     = T2 + Npad * 64;                 // Npad*128

    const int gN   = (N + 255) / 256;
    const int gN16 = (N * 16 + 255) / 256;
    const int nbin = (E + BIN_CHUNK - 1) / BIN_CHUNK;

    hipMemsetAsync(bcnt, 0, 256 * sizeof(int), stream);
    hipMemsetAsync(psum, 0, 512 * sizeof(float), stream);

    // ---- CSR build (by dst, col = src) + dinv
    bhist_kernel<<<256, 256, 0, stream>>>(dstp, bcnt, E, NB);
    bscan_kernel<<<1, 128, 0, stream>>>(bcnt, base, bfill, NB, E);
    bin_kernel<<<nbin, 256, 0, stream>>>(srcp, dstp, bfill, binned, E, NB);
    group_kernel<<<NB, 256, 0, stream>>>(binned, base, rowptr, col, dinv, N, E);

    // ---- layer 1: aggregate X (dim 64) first, then GEMM 64->128 + bias + relu
    scale_kernel<<<gN16, 256, 0, stream>>>(x, dinv, T1, N);
    gather_kernel<16, false><<<(N + 15) / 16, 256, 0, stream>>>(T1, rowptr, col, dinv, nullptr, T2, N);
    gemm_kernel<64, 128, 4, 0><<<(N + 31) / 32, 256, 0, stream>>>(T2, W1, b1, nullptr, H1, N);

    // ---- layer 2: GEMM 128->64 (scale by dinv), gather(bias+relu)
    gemm_kernel<128, 64, 2, 1><<<(N + 31) / 32, 256, 0, stream>>>(H1, W2, nullptr, dinv, T1, N);
    gather_kernel<16, true><<<(N + 15) / 16, 256, 0, stream>>>(T1, rowptr, col, dinv, b2, T2, N);

    // ---- layer 3: GEMM 64->64
    gemm_kernel<64, 64, 4, 1><<<(N + 63) / 64, 256, 0, stream>>>(T2, W3, nullptr, dinv, T1, N);
    gather_kernel<16, true><<<(N + 15) / 16, 256, 0, stream>>>(T1, rowptr, col, dinv, b3, T2, N);

    // ---- layer 4: GEMM 64->32
    gemm_kernel<64, 32, 4, 1><<<(N + 127) / 128, 256, 0, stream>>>(T2, W4, nullptr, dinv, T1, N);
    gather_kernel<8, true><<<(N + 31) / 32, 256, 0, stream>>>(T1, rowptr, col, dinv, b4, T2, N);

    // ---- pool + fc
    pool_kernel<<<gN, 256, 0, stream>>>(T2, Wfc, batch, psum, pcnt, N);
    final_kernel<<<1, 256, 0, stream>>>(psum, pcnt, bfc, out, G);
}